// Round 4
// baseline (1195.055 us; speedup 1.0000x reference)
//
#include <hip/hip_runtime.h>
#include <math.h>

#define N_CH 256
#define T_IN 100000
#define L1O 20000
#define L2O 4000
#define L3O 800
#define C1 8
#define C2 16
#define C3 32

// ---------- fused conv tile geometry ----------
#define TILE3 25      // conv3 outputs per block
#define NY2   125     // conv2 positions needed
#define NY1   627     // conv1 positions needed
#define ND    3141    // data samples needed

#define KEEP1(x) asm volatile("" : "+v"(x))

__device__ __forceinline__ float sigm(float x) {
    x = fminf(fmaxf(x, -30.0f), 30.0f);
    return 1.0f / (1.0f + __expf(-x));
}
__device__ __forceinline__ float tanhfast(float x) {
    x = fminf(fmaxf(x, -15.0f), 15.0f);
    float e = __expf(-2.0f * x);
    return (1.0f - e) / (1.0f + e);
}
__device__ __forceinline__ float dot4(float4 a, float4 b) {
    return a.x * b.x + a.y * b.y + a.z * b.z + a.w * b.w;
}
__device__ __forceinline__ float bcast(float v, int lane) {
    return __int_as_float(__builtin_amdgcn_readlane(__float_as_int(v), lane));
}

// ================= K1: fused conv1+conv2+conv3 =================
// grid (32 tiles, 256 channels), 256 threads
__global__ __launch_bounds__(256) void k_conv(
    const float* __restrict__ data,
    const float* __restrict__ w1, const float* __restrict__ b1,
    const float* __restrict__ w2, const float* __restrict__ b2,
    const float* __restrict__ w3, const float* __restrict__ b3,
    float* __restrict__ x3)
{
    __shared__ __align__(16) float sd[ND];
    __shared__ __align__(16) float sy1[NY1][C1];
    __shared__ __align__(16) float sy2[NY2][C2];
    __shared__ __align__(16) float sw1[C1 * 11];
    __shared__ float sb1[C1];
    __shared__ __align__(16) float sw2[C2 * C1 * 7];
    __shared__ float sb2[C2];
    __shared__ __align__(16) float sw3[C3 * C2 * 5];
    __shared__ float sb3[C3];

    const int tid = threadIdx.x;
    const int tb  = blockIdx.x;   // tile
    const int ch  = blockIdx.y;   // channel
    const int t0    = tb * TILE3;
    const int dbase = 3125 * tb - 70;
    const int ubase = 625 * tb - 13;
    const int sbase = 125 * tb - 2;

    for (int e = tid; e < C1 * 11;    e += 256) sw1[e] = w1[e];
    for (int e = tid; e < C1;         e += 256) sb1[e] = b1[e];
    for (int e = tid; e < C2 * C1 * 7; e += 256) sw2[e] = w2[e];
    for (int e = tid; e < C2;         e += 256) sb2[e] = b2[e];
    for (int e = tid; e < C3 * C2 * 5; e += 256) sw3[e] = w3[e];
    for (int e = tid; e < C3;         e += 256) sb3[e] = b3[e];

    const float* dch = data + (size_t)ch * T_IN;
    for (int e = tid; e < ND; e += 256) {
        int g = dbase + e;
        sd[e] = (g >= 0 && g < T_IN) ? dch[g] : 0.0f;
    }
    __syncthreads();

    // conv1 (stride 5, k=11, pad 5): thread owns out-channel c = tid&7
    {
        const int c = tid & 7;
        float wr[11];
        #pragma unroll
        for (int k = 0; k < 11; ++k) wr[k] = sw1[c * 11 + k];
        const float bb = sb1[c];
        for (int u = tid >> 3; u < NY1; u += 32) {
            int ug = ubase + u;
            float acc = bb;
            #pragma unroll
            for (int k = 0; k < 11; ++k) acc += wr[k] * sd[5 * u + k];
            sy1[u][c] = (ug >= 0 && ug < L1O) ? fmaxf(acc, 0.0f) : 0.0f;
        }
    }
    __syncthreads();

    // conv2 (stride 5, k=7, pad 3): thread owns out-channel c = tid&15
    {
        const int c = tid & 15;
        float wr[56];
        #pragma unroll
        for (int q = 0; q < 14; ++q)
            ((float4*)wr)[q] = ((const float4*)(sw2 + c * 56))[q];
        const float bb = sb2[c];
        for (int s = tid >> 4; s < NY2; s += 16) {
            int sg = sbase + s;
            float acc = bb;
            #pragma unroll
            for (int k = 0; k < 7; ++k) {
                const float4* y4 = (const float4*)&sy1[5 * s + k][0];
                float4 ya = y4[0], yb = y4[1];
                acc += wr[0*7+k]*ya.x + wr[1*7+k]*ya.y + wr[2*7+k]*ya.z + wr[3*7+k]*ya.w
                     + wr[4*7+k]*yb.x + wr[5*7+k]*yb.y + wr[6*7+k]*yb.z + wr[7*7+k]*yb.w;
            }
            sy2[s][c] = (sg >= 0 && sg < L2O) ? fmaxf(acc, 0.0f) : 0.0f;
        }
    }
    __syncthreads();

    // conv3 (stride 5, k=5, pad 2): thread owns out-channel o = tid&31
    {
        const int o = tid & 31;
        float wr[80];
        #pragma unroll
        for (int q = 0; q < 20; ++q)
            ((float4*)wr)[q] = ((const float4*)(sw3 + o * 80))[q];
        const float bb = sb3[o];
        for (int tl = tid >> 5; tl < TILE3; tl += 8) {
            float acc = bb;
            #pragma unroll
            for (int k = 0; k < 5; ++k) {
                const float4* y4 = (const float4*)&sy2[5 * tl + k][0];
                float4 za = y4[0], zb = y4[1], zc = y4[2], zd = y4[3];
                acc += wr[0*5+k]*za.x  + wr[1*5+k]*za.y  + wr[2*5+k]*za.z  + wr[3*5+k]*za.w
                     + wr[4*5+k]*zb.x  + wr[5*5+k]*zb.y  + wr[6*5+k]*zb.z  + wr[7*5+k]*zb.w
                     + wr[8*5+k]*zc.x  + wr[9*5+k]*zc.y  + wr[10*5+k]*zc.z + wr[11*5+k]*zc.w
                     + wr[12*5+k]*zd.x + wr[13*5+k]*zd.y + wr[14*5+k]*zd.z + wr[15*5+k]*zd.w;
            }
            x3[((size_t)ch * L3O + (t0 + tl)) * C3 + o] = fmaxf(acc, 0.0f);
        }
    }
}

// ================= K2: GRU recurrence — 3 waves per (ch,dir), 1 per gate ====
// Each lane holds only its gate row (64 whh + 32 wih regs). All waves keep a
// redundant full copy of h (one element per lane) and broadcast via readlane.
// Only gate pre-activations cross waves: 4 LDS floats + 1 barrier per step,
// parity double-buffered.
__global__ __launch_bounds__(192, 1) void k_gru4(
    const float* __restrict__ x3,
    const float* __restrict__ wih_f, const float* __restrict__ bih_f,
    const float* __restrict__ whh_f, const float* __restrict__ bhh_f,
    const float* __restrict__ wih_b, const float* __restrict__ bih_b,
    const float* __restrict__ whh_b, const float* __restrict__ bhh_b,
    float* __restrict__ hN)
{
    const int tid  = threadIdx.x;
    const int lane = tid & 63;
    const int g    = tid >> 6;          // 0=r, 1=z, 2=n
    const int ch = blockIdx.x, dir = blockIdx.y;
    const float* wih = dir ? wih_b : wih_f;
    const float* whh = dir ? whh_b : whh_f;
    const float* bih = dir ? bih_b : bih_f;
    const float* bhh = dir ? bhh_b : bhh_f;
    const int row = g * 64 + lane;

    __shared__ float sdot[2][4][64];

    // gate row of whh (64) and wih (32) in registers
    float w[64];
    {
        const float4* w4 = (const float4*)(whh + row * 64);
        #pragma unroll
        for (int q = 0; q < 16; ++q) {
            float4 v = w4[q];
            w[4*q] = v.x; w[4*q+1] = v.y; w[4*q+2] = v.z; w[4*q+3] = v.w;
        }
    }
    float wi[32];
    {
        const float4* w4 = (const float4*)(wih + row * 32);
        #pragma unroll
        for (int q = 0; q < 8; ++q) {
            float4 v = w4[q];
            wi[4*q] = v.x; wi[4*q+1] = v.y; wi[4*q+2] = v.z; wi[4*q+3] = v.w;
        }
    }
    #pragma unroll
    for (int j = 0; j < 64; ++j) KEEP1(w[j]);
    #pragma unroll
    for (int j = 0; j < 32; ++j) KEEP1(wi[j]);

    const float bi = bih[row];
    const float bh = bhh[row];

    // per-step x element this lane loads: x3[ch][t][lane&31]
    const float* xp = x3 + (size_t)ch * L3O * 32 + (lane & 31);
    const int xstride = dir ? -32 : 32;
    if (dir) xp += (size_t)(L3O - 1) * 32;

    float x0 = xp[0]; xp += xstride;
    float x1 = xp[0]; xp += xstride;
    float x2 = xp[0]; xp += xstride;

    float h = 0.0f;

    for (int s = 0; s < L3O; ++s) {
        float xnext = 0.0f;
        if (s + 3 < L3O) xnext = xp[0];
        xp += xstride;

        // input dot: i_g = x . wih_row + bi
        float a0 = bi, a0b = 0.0f;
        #pragma unroll
        for (int k = 0; k < 32; k += 2) {
            a0  = fmaf(wi[k],     bcast(x0, k),     a0);
            a0b = fmaf(wi[k + 1], bcast(x0, k + 1), a0b);
        }
        // hidden dot: hd_g = h . whh_row + bh
        float a1 = bh, a1b = 0.0f, a1c = 0.0f, a1d = 0.0f;
        #pragma unroll
        for (int j = 0; j < 64; j += 4) {
            a1  = fmaf(w[j],     bcast(h, j),     a1);
            a1b = fmaf(w[j + 1], bcast(h, j + 1), a1b);
            a1c = fmaf(w[j + 2], bcast(h, j + 2), a1c);
            a1d = fmaf(w[j + 3], bcast(h, j + 3), a1d);
        }
        float ai = a0 + a0b;                       // input part (incl bih)
        float ah = (a1 + a1b) + (a1c + a1d);       // hidden part (incl bhh)

        const int p = s & 1;
        if (g < 2) {
            sdot[p][g][lane] = ai + ah;            // full pre-act for r,z
        } else {
            sdot[p][2][lane] = ah;                 // hidden part for n
            sdot[p][3][lane] = ai;                 // input part for n
        }
        __syncthreads();

        float sr  = sdot[p][0][lane];
        float sz  = sdot[p][1][lane];
        float shn = sdot[p][2][lane];
        float sin_= sdot[p][3][lane];
        float r = sigm(sr);
        float z = sigm(sz);
        float n = tanhfast(sin_ + r * shn);
        h = (1.0f - z) * n + z * h;

        x0 = x1; x1 = x2; x2 = xnext;
    }
    if (g == 0) hN[ch * 128 + dir * 64 + lane] = h;
}

// ================= K3a: row normalize + hw1 = h_n @ gcn1_w.T =================
__global__ __launch_bounds__(128) void k_norm(
    const float* __restrict__ hN, const float* __restrict__ gcn1_w,
    float* __restrict__ Xn, float* __restrict__ XnT, float* __restrict__ hw1)
{
    const int i = blockIdx.x, tid = threadIdx.x;
    __shared__ float red[128];
    __shared__ float row[128];
    float v = hN[i * 128 + tid];
    row[tid] = v;
    red[tid] = v;
    __syncthreads();
    for (int s = 64; s > 0; s >>= 1) { if (tid < s) red[tid] += red[tid + s]; __syncthreads(); }
    float mean = red[0] / 128.0f;
    __syncthreads();
    float d = v - mean;
    red[tid] = d * d;
    __syncthreads();
    for (int s = 64; s > 0; s >>= 1) { if (tid < s) red[tid] += red[tid + s]; __syncthreads(); }
    float sd = sqrtf(red[0] / 127.0f);
    float xn = d / (sd + 1e-6f);
    Xn[i * 128 + tid] = xn;
    XnT[tid * 256 + i] = xn;
    if (tid < 32) {
        float acc = 0.f;
        for (int k = 0; k < 128; ++k) acc += row[k] * gcn1_w[tid * 128 + k];
        hw1[i * 32 + tid] = acc;
    }
}

// ================= K3b: corr row -> adjacency + degree =================
__global__ __launch_bounds__(256) void k_corr(
    const float* __restrict__ Xn, const float* __restrict__ XnT,
    float* __restrict__ A, float* __restrict__ deg)
{
    const int i = blockIdx.x, tid = threadIdx.x;
    __shared__ float xi[128];
    __shared__ float red[256];
    if (tid < 128) xi[tid] = Xn[i * 128 + tid];
    __syncthreads();
    float c = 0.f;
    for (int k = 0; k < 128; ++k) c += xi[k] * XnT[k * 256 + tid];
    c *= (1.0f / 128.0f);
    float a = (fabsf(c) > 0.7f) ? 1.0f : 0.0f;
    A[i * 256 + tid] = a;
    red[tid] = a;
    __syncthreads();
    for (int s = 128; s > 0; s >>= 1) { if (tid < s) red[tid] += red[tid + s]; __syncthreads(); }
    if (tid == 0) deg[i] = red[0];
}

// ================= K3c/d: GCN layer (+ optional next-layer feature GEMM) =====
__global__ __launch_bounds__(256) void k_gcn(
    const float* __restrict__ A, const float* __restrict__ deg,
    const float* __restrict__ hw, const float* __restrict__ bias,
    const float* __restrict__ wNext,
    float* __restrict__ hOut, float* __restrict__ hwNext)
{
    const int i = blockIdx.x, tid = threadIdx.x;
    const int f = tid & 31, grp = tid >> 5;
    __shared__ float aj[256];
    __shared__ float red[8][32];
    __shared__ float hrow[32];
    float dj = rsqrtf(fmaxf(deg[tid], 1e-12f));
    aj[tid] = A[i * 256 + tid] * dj;
    __syncthreads();
    float p = 0.f;
    for (int j = grp * 32; j < grp * 32 + 32; ++j) p += aj[j] * hw[j * 32 + f];
    red[grp][f] = p;
    __syncthreads();
    if (grp == 0) {
        float s = 0.f;
        #pragma unroll
        for (int g = 0; g < 8; ++g) s += red[g][f];
        float di = rsqrtf(fmaxf(deg[i], 1e-12f));
        float o = fmaxf(bias[f] + di * s, 0.0f);
        hOut[i * 32 + f] = o;
        hrow[f] = o;
    }
    __syncthreads();
    if (wNext != nullptr && grp == 0) {
        float acc = 0.f;
        #pragma unroll
        for (int k = 0; k < 32; ++k) acc += hrow[k] * wNext[f * 32 + k];
        hwNext[i * 32 + f] = acc;
    }
}

// ================= K3e: mean + classifier =================
__global__ __launch_bounds__(64) void k_head(
    const float* __restrict__ h2, const float* __restrict__ cls_w,
    const float* __restrict__ cls_b, float* __restrict__ out)
{
    const int tid = threadIdx.x;
    __shared__ float mean[32];
    if (tid < 32) {
        float s = 0.f;
        for (int i = 0; i < 256; ++i) s += h2[i * 32 + tid];
        mean[tid] = s * (1.0f / 256.0f);
    }
    __syncthreads();
    if (tid < 2) {
        float s = cls_b[tid];
        #pragma unroll
        for (int fe = 0; fe < 32; ++fe) s += mean[fe] * cls_w[tid * 32 + fe];
        out[tid] = s;
    }
}

extern "C" void kernel_launch(void* const* d_in, const int* in_sizes, int n_in,
                              void* d_out, int out_size, void* d_ws, size_t ws_size,
                              hipStream_t stream) {
    const float* data    = (const float*)d_in[0];
    const float* conv1_w = (const float*)d_in[1];
    const float* conv1_b = (const float*)d_in[2];
    const float* conv2_w = (const float*)d_in[3];
    const float* conv2_b = (const float*)d_in[4];
    const float* conv3_w = (const float*)d_in[5];
    const float* conv3_b = (const float*)d_in[6];
    const float* wih_f   = (const float*)d_in[7];
    const float* whh_f   = (const float*)d_in[8];
    const float* bih_f   = (const float*)d_in[9];
    const float* bhh_f   = (const float*)d_in[10];
    const float* wih_b   = (const float*)d_in[11];
    const float* whh_b   = (const float*)d_in[12];
    const float* bih_b   = (const float*)d_in[13];
    const float* bhh_b   = (const float*)d_in[14];
    const float* gcn1_w  = (const float*)d_in[15];
    const float* gcn1_b  = (const float*)d_in[16];
    const float* gcn2_w  = (const float*)d_in[17];
    const float* gcn2_b  = (const float*)d_in[18];
    const float* cls_w   = (const float*)d_in[19];
    const float* cls_b   = (const float*)d_in[20];

    float* ws  = (float*)d_ws;
    float* x3  = ws;                   // 256*800*32 = 6,553,600
    float* hN  = x3 + 6553600;         // 256*128
    float* Xn  = hN + 32768;           // 256*128
    float* XnT = Xn + 32768;           // 128*256
    float* A   = XnT + 32768;          // 256*256
    float* deg = A + 65536;            // 256
    float* hw1 = deg + 256;            // 256*32
    float* h1  = hw1 + 8192;           // 256*32
    float* hw2 = h1 + 8192;            // 256*32
    float* h2  = hw2 + 8192;           // 256*32

    k_conv<<<dim3(32, 256), 256, 0, stream>>>(data, conv1_w, conv1_b, conv2_w, conv2_b,
                                              conv3_w, conv3_b, x3);
    k_gru4<<<dim3(256, 2), 192, 0, stream>>>(x3, wih_f, bih_f, whh_f, bhh_f,
                                             wih_b, bih_b, whh_b, bhh_b, hN);
    k_norm<<<256, 128, 0, stream>>>(hN, gcn1_w, Xn, XnT, hw1);
    k_corr<<<256, 256, 0, stream>>>(Xn, XnT, A, deg);
    k_gcn<<<256, 256, 0, stream>>>(A, deg, hw1, gcn1_b, gcn2_w, h1, hw2);
    k_gcn<<<256, 256, 0, stream>>>(A, deg, hw2, gcn2_b, nullptr, h2, nullptr);
    k_head<<<1, 64, 0, stream>>>(h2, cls_w, cls_b, (float*)d_out);
}

// Round 5
// 1093.249 us; speedup vs baseline: 1.0931x; 1.0931x over previous
//
#include <hip/hip_runtime.h>
#include <math.h>

#define N_CH 256
#define T_IN 100000
#define L1O 20000
#define L2O 4000
#define L3O 800
#define C1 8
#define C2 16
#define C3 32

// ---------- fused conv tile geometry ----------
#define TILE3 25      // conv3 outputs per block
#define NY2   125     // conv2 positions needed
#define NY1   627     // conv1 positions needed
#define ND    3141    // data samples needed

__device__ __forceinline__ float sigm(float x) {
    x = fminf(fmaxf(x, -30.0f), 30.0f);
    return 1.0f / (1.0f + __expf(-x));
}
__device__ __forceinline__ float tanhfast(float x) {
    x = fminf(fmaxf(x, -15.0f), 15.0f);
    float e = __expf(-2.0f * x);
    return (1.0f - e) / (1.0f + e);
}
__device__ __forceinline__ float bcast(float v, int lane) {
    return __int_as_float(__builtin_amdgcn_readlane(__float_as_int(v), lane));
}
__device__ __forceinline__ float f4e(const float4& v, int e) {
    return ((const float*)&v)[e];
}

// ================= K1: fused conv1+conv2+conv3, by-position =================
// Threads own positions; taps staged to registers; weights read with
// wave-uniform indices from global (scalarized to s_load -> off LDS pipe).
__global__ __launch_bounds__(256) void k_conv(
    const float* __restrict__ data,
    const float* __restrict__ w1, const float* __restrict__ b1,
    const float* __restrict__ w2, const float* __restrict__ b2,
    const float* __restrict__ w3, const float* __restrict__ b3,
    float* __restrict__ x3)
{
    __shared__ __align__(16) float sd[ND];
    __shared__ __align__(16) float sy1[NY1][C1];
    __shared__ __align__(16) float sy2[NY2][C2];

    const int tid = threadIdx.x;
    const int tb  = blockIdx.x;   // tile
    const int ch  = blockIdx.y;   // channel
    const int t0    = tb * TILE3;
    const int dbase = 3125 * tb - 70;
    const int ubase = 625 * tb - 13;
    const int sbase = 125 * tb - 2;

    const float* dch = data + (size_t)ch * T_IN;
    for (int e = tid; e < ND; e += 256) {
        int g = dbase + e;
        sd[e] = (g >= 0 && g < T_IN) ? dch[g] : 0.0f;
    }
    __syncthreads();

    // ---- conv1 (stride 5, k=11, pad 5): thread = position u ----
    for (int u = tid; u < NY1; u += 256) {
        int ug = ubase + u;
        bool ok = (ug >= 0 && ug < L1O);
        float t[11];
        #pragma unroll
        for (int k = 0; k < 11; ++k) t[k] = sd[5 * u + k];
        float acc[8];
        #pragma unroll
        for (int c = 0; c < 8; ++c) acc[c] = b1[c];
        #pragma unroll
        for (int k = 0; k < 11; ++k) {
            float tv = t[k];
            #pragma unroll
            for (int c = 0; c < 8; ++c) acc[c] = fmaf(w1[c * 11 + k], tv, acc[c]);
        }
        float4 o0, o1;
        o0.x = ok ? fmaxf(acc[0], 0.f) : 0.f;  o0.y = ok ? fmaxf(acc[1], 0.f) : 0.f;
        o0.z = ok ? fmaxf(acc[2], 0.f) : 0.f;  o0.w = ok ? fmaxf(acc[3], 0.f) : 0.f;
        o1.x = ok ? fmaxf(acc[4], 0.f) : 0.f;  o1.y = ok ? fmaxf(acc[5], 0.f) : 0.f;
        o1.z = ok ? fmaxf(acc[6], 0.f) : 0.f;  o1.w = ok ? fmaxf(acc[7], 0.f) : 0.f;
        ((float4*)&sy1[u][0])[0] = o0;
        ((float4*)&sy1[u][0])[1] = o1;
    }
    __syncthreads();

    // ---- conv2 (stride 5, k=7, pad 3): thread = (position s, out-chan half) ----
    {
        const int s    = tid & 127;          // position
        const int half = tid >> 7;           // wave-uniform out-channel half
        if (s < NY2) {
            int sg = sbase + s;
            bool ok = (sg >= 0 && sg < L2O);
            float tp[56];                    // taps [k][ci]
            #pragma unroll
            for (int k = 0; k < 7; ++k) {
                float4 a = ((const float4*)&sy1[5 * s + k][0])[0];
                float4 b = ((const float4*)&sy1[5 * s + k][0])[1];
                tp[k * 8 + 0] = a.x; tp[k * 8 + 1] = a.y; tp[k * 8 + 2] = a.z; tp[k * 8 + 3] = a.w;
                tp[k * 8 + 4] = b.x; tp[k * 8 + 5] = b.y; tp[k * 8 + 6] = b.z; tp[k * 8 + 7] = b.w;
            }
            const int c0 = half * 8;
            float acc[8];
            #pragma unroll
            for (int cc = 0; cc < 8; ++cc) acc[cc] = b2[c0 + cc];
            #pragma unroll
            for (int cc = 0; cc < 8; ++cc) {
                const float* wp = w2 + (c0 + cc) * 56;   // wave-uniform base
                float a = acc[cc];
                #pragma unroll
                for (int ci = 0; ci < 8; ++ci)
                    #pragma unroll
                    for (int k = 0; k < 7; ++k)
                        a = fmaf(wp[ci * 7 + k], tp[k * 8 + ci], a);
                acc[cc] = a;
            }
            float4 o0, o1;
            o0.x = ok ? fmaxf(acc[0], 0.f) : 0.f;  o0.y = ok ? fmaxf(acc[1], 0.f) : 0.f;
            o0.z = ok ? fmaxf(acc[2], 0.f) : 0.f;  o0.w = ok ? fmaxf(acc[3], 0.f) : 0.f;
            o1.x = ok ? fmaxf(acc[4], 0.f) : 0.f;  o1.y = ok ? fmaxf(acc[5], 0.f) : 0.f;
            o1.z = ok ? fmaxf(acc[6], 0.f) : 0.f;  o1.w = ok ? fmaxf(acc[7], 0.f) : 0.f;
            ((float4*)&sy2[s][c0])[0] = o0;
            ((float4*)&sy2[s][c0])[1] = o1;
        }
    }
    __syncthreads();

    // ---- conv3 (stride 5, k=5, pad 2): thread = (position s, out-chan half) ----
    {
        const int s    = tid & 127;
        const int half = tid >> 7;           // wave-uniform
        if (s < TILE3) {
            float tp[80];                    // taps [k][ci]
            #pragma unroll
            for (int k = 0; k < 5; ++k) {
                #pragma unroll
                for (int q = 0; q < 4; ++q) {
                    float4 a = ((const float4*)&sy2[5 * s + k][0])[q];
                    tp[k * 16 + q * 4 + 0] = a.x; tp[k * 16 + q * 4 + 1] = a.y;
                    tp[k * 16 + q * 4 + 2] = a.z; tp[k * 16 + q * 4 + 3] = a.w;
                }
            }
            const int o0 = half * 16;
            float* xo = x3 + ((size_t)ch * L3O + (t0 + s)) * C3 + o0;
            #pragma unroll
            for (int oo = 0; oo < 16; ++oo) {
                const float* wp = w3 + (o0 + oo) * 80;   // wave-uniform base
                float a = b3[o0 + oo];
                #pragma unroll
                for (int ci = 0; ci < 16; ++ci)
                    #pragma unroll
                    for (int k = 0; k < 5; ++k)
                        a = fmaf(wp[ci * 5 + k], tp[k * 16 + ci], a);
                xo[oo] = fmaxf(a, 0.f);
            }
        }
    }
}

// ================= K2: GRU recurrence — 4 waves per (ch,dir), K-split =======
// Lane l owns gate rows (l, 64+l, 128+l); wave w owns K-quarter
// (h[16w:16w+16), x[8w:8w+8)) -> only 72 weight VGPRs/lane. Every wave keeps
// a redundant full h copy (lane l holds h_l), broadcast via readlane.
// Partials cross waves through LDS: 4 floats/lane + ONE barrier per step
// (parity double-buffered).
__global__ __launch_bounds__(256) void k_gru5(
    const float* __restrict__ x3,
    const float* __restrict__ wih_f, const float* __restrict__ bih_f,
    const float* __restrict__ whh_f, const float* __restrict__ bhh_f,
    const float* __restrict__ wih_b, const float* __restrict__ bih_b,
    const float* __restrict__ whh_b, const float* __restrict__ bhh_b,
    float* __restrict__ hN)
{
    const int tid = threadIdx.x;
    const int l   = tid & 63;
    const int w   = tid >> 6;            // K-quarter (wave index)
    const int ch = blockIdx.x, dir = blockIdx.y;
    const float* wih = dir ? wih_b : wih_f;
    const float* whh = dir ? whh_b : whh_f;
    const float* bih = dir ? bih_b : bih_f;
    const float* bhh = dir ? bhh_b : bhh_f;

    __shared__ float sdot[2][4][4][64];

    // 48 whh + 24 wih weights per lane (float4-packed)
    float4 whq[12];                       // [g*4+q], K-range [16w,16w+16)
    #pragma unroll
    for (int g = 0; g < 3; ++g)
        #pragma unroll
        for (int q = 0; q < 4; ++q)
            whq[g * 4 + q] = *(const float4*)&whh[(g * 64 + l) * 64 + w * 16 + q * 4];
    float4 wiq[6];                        // [g*2+q], K-range [8w,8w+8)
    #pragma unroll
    for (int g = 0; g < 3; ++g)
        #pragma unroll
        for (int q = 0; q < 2; ++q)
            wiq[g * 2 + q] = *(const float4*)&wih[(g * 64 + l) * 32 + w * 8 + q * 4];

    const float br   = bih[l] + bhh[l];
    const float bz   = bih[64 + l] + bhh[64 + l];
    const float bin_ = bih[128 + l];
    const float bhn  = bhh[128 + l];

    // per-step x element: x3[ch][t][l&31], 3-deep prefetch
    const float* xp = x3 + (size_t)ch * L3O * 32 + (l & 31);
    const int xstride = dir ? -32 : 32;
    if (dir) xp += (size_t)(L3O - 1) * 32;
    float x0 = xp[0]; xp += xstride;
    float x1 = xp[0]; xp += xstride;
    float x2 = xp[0]; xp += xstride;

    float h = 0.0f;
    const int kb = w * 16;               // h broadcast base (SGPR)
    const int xb = w * 8;                // x broadcast base (SGPR)

    for (int s = 0; s < L3O; ++s) {
        float xn_ = 0.0f;
        if (s + 3 < L3O) xn_ = xp[0];
        xp += xstride;

        // hidden partial dots over this wave's K-quarter
        float pr = 0.f, pz = 0.f, pn = 0.f;
        #pragma unroll
        for (int q = 0; q < 4; ++q)
            #pragma unroll
            for (int e = 0; e < 4; ++e) {
                float hb = bcast(h, kb + q * 4 + e);
                pr = fmaf(f4e(whq[q],     e), hb, pr);
                pz = fmaf(f4e(whq[4 + q], e), hb, pz);
                pn = fmaf(f4e(whq[8 + q], e), hb, pn);
            }
        // input partial dots over this wave's x-eighth
        float ir = 0.f, iz = 0.f, in_ = 0.f;
        #pragma unroll
        for (int q = 0; q < 2; ++q)
            #pragma unroll
            for (int e = 0; e < 4; ++e) {
                float xv = bcast(x0, xb + q * 4 + e);
                ir  = fmaf(f4e(wiq[q],     e), xv, ir);
                iz  = fmaf(f4e(wiq[2 + q], e), xv, iz);
                in_ = fmaf(f4e(wiq[4 + q], e), xv, in_);
            }

        const int p = s & 1;
        sdot[p][w][0][l] = pr + ir;
        sdot[p][w][1][l] = pz + iz;
        sdot[p][w][2][l] = pn;           // hidden-only (for r-gating)
        sdot[p][w][3][l] = in_;          // input-only
        __syncthreads();

        float sr = br, sz_ = bz, snh = bhn, sni = bin_;
        #pragma unroll
        for (int ww = 0; ww < 4; ++ww) {
            sr  += sdot[p][ww][0][l];
            sz_ += sdot[p][ww][1][l];
            snh += sdot[p][ww][2][l];
            sni += sdot[p][ww][3][l];
        }
        float r = sigm(sr);
        float z = sigm(sz_);
        float n = tanhfast(sni + r * snh);
        h = (1.0f - z) * n + z * h;

        x0 = x1; x1 = x2; x2 = xn_;
    }
    if (w == 0) hN[ch * 128 + dir * 64 + l] = h;
}

// ================= K3a: row normalize + hw1 = h_n @ gcn1_w.T =================
__global__ __launch_bounds__(128) void k_norm(
    const float* __restrict__ hN, const float* __restrict__ gcn1_w,
    float* __restrict__ Xn, float* __restrict__ XnT, float* __restrict__ hw1)
{
    const int i = blockIdx.x, tid = threadIdx.x;
    __shared__ float red[128];
    __shared__ float row[128];
    float v = hN[i * 128 + tid];
    row[tid] = v;
    red[tid] = v;
    __syncthreads();
    for (int s = 64; s > 0; s >>= 1) { if (tid < s) red[tid] += red[tid + s]; __syncthreads(); }
    float mean = red[0] / 128.0f;
    __syncthreads();
    float d = v - mean;
    red[tid] = d * d;
    __syncthreads();
    for (int s = 64; s > 0; s >>= 1) { if (tid < s) red[tid] += red[tid + s]; __syncthreads(); }
    float sd = sqrtf(red[0] / 127.0f);
    float xn = d / (sd + 1e-6f);
    Xn[i * 128 + tid] = xn;
    XnT[tid * 256 + i] = xn;
    if (tid < 32) {
        float acc = 0.f;
        for (int k = 0; k < 128; ++k) acc += row[k] * gcn1_w[tid * 128 + k];
        hw1[i * 32 + tid] = acc;
    }
}

// ================= K3b: corr row -> adjacency + degree =================
__global__ __launch_bounds__(256) void k_corr(
    const float* __restrict__ Xn, const float* __restrict__ XnT,
    float* __restrict__ A, float* __restrict__ deg)
{
    const int i = blockIdx.x, tid = threadIdx.x;
    __shared__ float xi[128];
    __shared__ float red[256];
    if (tid < 128) xi[tid] = Xn[i * 128 + tid];
    __syncthreads();
    float c = 0.f;
    for (int k = 0; k < 128; ++k) c += xi[k] * XnT[k * 256 + tid];
    c *= (1.0f / 128.0f);
    float a = (fabsf(c) > 0.7f) ? 1.0f : 0.0f;
    A[i * 256 + tid] = a;
    red[tid] = a;
    __syncthreads();
    for (int s = 128; s > 0; s >>= 1) { if (tid < s) red[tid] += red[tid + s]; __syncthreads(); }
    if (tid == 0) deg[i] = red[0];
}

// ================= K3c/d: GCN layer (+ optional next-layer feature GEMM) =====
__global__ __launch_bounds__(256) void k_gcn(
    const float* __restrict__ A, const float* __restrict__ deg,
    const float* __restrict__ hw, const float* __restrict__ bias,
    const float* __restrict__ wNext,
    float* __restrict__ hOut, float* __restrict__ hwNext)
{
    const int i = blockIdx.x, tid = threadIdx.x;
    const int f = tid & 31, grp = tid >> 5;
    __shared__ float aj[256];
    __shared__ float red[8][32];
    __shared__ float hrow[32];
    float dj = rsqrtf(fmaxf(deg[tid], 1e-12f));
    aj[tid] = A[i * 256 + tid] * dj;
    __syncthreads();
    float p = 0.f;
    for (int j = grp * 32; j < grp * 32 + 32; ++j) p += aj[j] * hw[j * 32 + f];
    red[grp][f] = p;
    __syncthreads();
    if (grp == 0) {
        float s = 0.f;
        #pragma unroll
        for (int g = 0; g < 8; ++g) s += red[g][f];
        float di = rsqrtf(fmaxf(deg[i], 1e-12f));
        float o = fmaxf(bias[f] + di * s, 0.0f);
        hOut[i * 32 + f] = o;
        hrow[f] = o;
    }
    __syncthreads();
    if (wNext != nullptr && grp == 0) {
        float acc = 0.f;
        #pragma unroll
        for (int k = 0; k < 32; ++k) acc += hrow[k] * wNext[f * 32 + k];
        hwNext[i * 32 + f] = acc;
    }
}

// ================= K3e: mean + classifier =================
__global__ __launch_bounds__(64) void k_head(
    const float* __restrict__ h2, const float* __restrict__ cls_w,
    const float* __restrict__ cls_b, float* __restrict__ out)
{
    const int tid = threadIdx.x;
    __shared__ float mean[32];
    if (tid < 32) {
        float s = 0.f;
        for (int i = 0; i < 256; ++i) s += h2[i * 32 + tid];
        mean[tid] = s * (1.0f / 256.0f);
    }
    __syncthreads();
    if (tid < 2) {
        float s = cls_b[tid];
        #pragma unroll
        for (int fe = 0; fe < 32; ++fe) s += mean[fe] * cls_w[tid * 32 + fe];
        out[tid] = s;
    }
}

extern "C" void kernel_launch(void* const* d_in, const int* in_sizes, int n_in,
                              void* d_out, int out_size, void* d_ws, size_t ws_size,
                              hipStream_t stream) {
    const float* data    = (const float*)d_in[0];
    const float* conv1_w = (const float*)d_in[1];
    const float* conv1_b = (const float*)d_in[2];
    const float* conv2_w = (const float*)d_in[3];
    const float* conv2_b = (const float*)d_in[4];
    const float* conv3_w = (const float*)d_in[5];
    const float* conv3_b = (const float*)d_in[6];
    const float* wih_f   = (const float*)d_in[7];
    const float* whh_f   = (const float*)d_in[8];
    const float* bih_f   = (const float*)d_in[9];
    const float* bhh_f   = (const float*)d_in[10];
    const float* wih_b   = (const float*)d_in[11];
    const float* whh_b   = (const float*)d_in[12];
    const float* bih_b   = (const float*)d_in[13];
    const float* bhh_b   = (const float*)d_in[14];
    const float* gcn1_w  = (const float*)d_in[15];
    const float* gcn1_b  = (const float*)d_in[16];
    const float* gcn2_w  = (const float*)d_in[17];
    const float* gcn2_b  = (const float*)d_in[18];
    const float* cls_w   = (const float*)d_in[19];
    const float* cls_b   = (const float*)d_in[20];

    float* ws  = (float*)d_ws;
    float* x3  = ws;                   // 256*800*32 = 6,553,600
    float* hN  = x3 + 6553600;         // 256*128
    float* Xn  = hN + 32768;           // 256*128
    float* XnT = Xn + 32768;           // 128*256
    float* A   = XnT + 32768;          // 256*256
    float* deg = A + 65536;            // 256
    float* hw1 = deg + 256;            // 256*32
    float* h1  = hw1 + 8192;           // 256*32
    float* hw2 = h1 + 8192;            // 256*32
    float* h2  = hw2 + 8192;           // 256*32

    k_conv<<<dim3(32, 256), 256, 0, stream>>>(data, conv1_w, conv1_b, conv2_w, conv2_b,
                                              conv3_w, conv3_b, x3);
    k_gru5<<<dim3(256, 2), 256, 0, stream>>>(x3, wih_f, bih_f, whh_f, bhh_f,
                                             wih_b, bih_b, whh_b, bhh_b, hN);
    k_norm<<<256, 128, 0, stream>>>(hN, gcn1_w, Xn, XnT, hw1);
    k_corr<<<256, 256, 0, stream>>>(Xn, XnT, A, deg);
    k_gcn<<<256, 256, 0, stream>>>(A, deg, hw1, gcn1_b, gcn2_w, h1, hw2);
    k_gcn<<<256, 256, 0, stream>>>(A, deg, hw2, gcn2_b, nullptr, h2, nullptr);
    k_head<<<1, 64, 0, stream>>>(h2, cls_w, cls_b, (float*)d_out);
}